// Round 1
// baseline (735.406 us; speedup 1.0000x reference)
//
#include <hip/hip_runtime.h>

// SGAT layer — fp32 in/out. R6: coalesce edge_kernel's ef read (was per-lane
// 512B stride = 64 lines/instr, TA issue-bound): 16 lanes cooperate per edge,
// wave-iteration reads 2KB contiguous (4 edges), B[128][4] held in 32 regs
// per lane, 4-step shfl_xor reduce, leader-lane epilogue. Also: sdot fused
// into gemm_wh epilogue (cross-lane reduce of fp32 acc vs a_src/a_dst; kills
// a launch + 12.8MB Whb re-read), fold merged into hist block 0.
// Kept from R5 (passed, absmax 3.7e-4, 710us): counting-sort by dst
// (hist+scan+bucket write) + per-node gather agg; bf16 MFMA Wh; global
// softmax w/o max-subtract; per-block exp-sum partials + tree reduce.

typedef __attribute__((ext_vector_type(8))) short short8;
typedef __attribute__((ext_vector_type(4))) float f32x4;

#define ALPHA 0.2f

__device__ __forceinline__ unsigned short f2bf(float f) {
    unsigned u = __float_as_uint(f);
    u += 0x7fffu + ((u >> 16) & 1u);
    return (unsigned short)(u >> 16);
}
__device__ __forceinline__ float bf2f(unsigned short u) {
    return __uint_as_float(((unsigned)u) << 16);
}

// deg[dst]++ over all edges; block 0 also folds B[k][h] = sum_d We[k][h*32+d]*a_edge[h*32+d]
__global__ void hist_fold_kernel(const int* __restrict__ ei, int* __restrict__ deg, int E,
                                 const float* __restrict__ We,
                                 const float* __restrict__ a_edge,
                                 float* __restrict__ Bfold) {
    if (blockIdx.x == 0 && threadIdx.x < 128) {
        int k = threadIdx.x;
        for (int h = 0; h < 4; h++) {
            float acc = 0.f;
            for (int d = 0; d < 32; d++)
                acc += We[k * 128 + h * 32 + d] * a_edge[h * 32 + d];
            Bfold[k * 4 + h] = acc;
        }
    }
    int e = blockIdx.x * blockDim.x + threadIdx.x;
    if (e < E) atomicAdd(&deg[ei[(size_t)E + e]], 1);
}

// single-block exclusive prefix sum: off[i] = sum deg[0..i), off[N] = E; cursor = off
__global__ __launch_bounds__(1024) void scan_kernel(const int* __restrict__ deg,
                                                    int* __restrict__ off,
                                                    int* __restrict__ cursor, int N) {
    __shared__ int buf[1024];
    int t = threadIdx.x;
    int base = 0;
    for (int start = 0; start < N; start += 8192) {
        int v[8];
        int tsum = 0;
#pragma unroll
        for (int j = 0; j < 8; j++) {
            int i = start + t * 8 + j;
            v[j] = (i < N) ? deg[i] : 0;
            tsum += v[j];
        }
        buf[t] = tsum;
        __syncthreads();
        for (int st = 1; st < 1024; st <<= 1) {
            int x = buf[t];
            int y = (t >= st) ? buf[t - st] : 0;
            __syncthreads();
            buf[t] = x + y;
            __syncthreads();
        }
        int excl = base + buf[t] - tsum;
        int chunk_total = buf[1023];
#pragma unroll
        for (int j = 0; j < 8; j++) {
            int i = start + t * 8 + j;
            if (i < N) { off[i] = excl; cursor[i] = excl; }
            excl += v[j];
        }
        base += chunk_total;
        __syncthreads();
    }
    if (t == 0) off[N] = base;
}

// Wh = h @ W : [N,128]x[128,128], fp32 in -> bf16 MFMA 16x16x32 -> bf16 out.
// Fused epilogue: s_src[n,h] = Wh[n,h*32:].a_src[h] (and s_dst) computed from
// the fp32 accumulators via 16-lane (column) shuffle reduce per head pair.
__global__ __launch_bounds__(256) void gemm_wh(const float* __restrict__ hmat,
                                               const float* __restrict__ W,
                                               const float* __restrict__ a_src,
                                               const float* __restrict__ a_dst,
                                               unsigned short* __restrict__ Whb,
                                               float* __restrict__ s_src,
                                               float* __restrict__ s_dst, int N) {
    __shared__ short Wb[16384];  // 32KB, [nt][ks][lane][j] fragment-contiguous
    int tid = threadIdx.x;
    for (int i = tid; i < 16384; i += 256) {
        int j = i & 7, lane = (i >> 3) & 63, ks = (i >> 9) & 3, nt = (i >> 11) & 7;
        int m = lane & 15, quad = lane >> 4;
        int k = ks * 32 + quad * 8 + j;
        int c = nt * 16 + m;
        Wb[i] = (short)f2bf(W[k * 128 + c]);
    }
    __syncthreads();
    int wave = tid >> 6, lane = tid & 63;
    int m = lane & 15, quad = lane >> 4;
    int row0 = blockIdx.x * 64 + wave * 16;
    int row = row0 + m;
    if (row >= N) row = N - 1;  // clamp loads; stores guarded below
    const float* hrow = hmat + (size_t)row * 128;
    short8 af[4];
    for (int ks = 0; ks < 4; ks++) {
        f32x4 lo = *(const f32x4*)(hrow + ks * 32 + quad * 8);
        f32x4 hi = *(const f32x4*)(hrow + ks * 32 + quad * 8 + 4);
        short8 a;
        a[0] = (short)f2bf(lo.x); a[1] = (short)f2bf(lo.y);
        a[2] = (short)f2bf(lo.z); a[3] = (short)f2bf(lo.w);
        a[4] = (short)f2bf(hi.x); a[5] = (short)f2bf(hi.y);
        a[6] = (short)f2bf(hi.z); a[7] = (short)f2bf(hi.w);
        af[ks] = a;
    }
    float ssrc[4] = {0.f, 0.f, 0.f, 0.f};
    float sdst[4] = {0.f, 0.f, 0.f, 0.f};
    for (int nt = 0; nt < 8; nt++) {
        f32x4 acc = {0.f, 0.f, 0.f, 0.f};
        for (int ks = 0; ks < 4; ks++) {
            short8 bf = *(const short8*)(Wb + ((nt * 4 + ks) * 64 + lane) * 8);
            acc = __builtin_amdgcn_mfma_f32_16x16x32_bf16(af[ks], bf, acc, 0, 0, 0);
        }
        // C/D: col = lane&15, row = quad*4 + r   [verified m89/m91]
        float as = a_src[nt * 16 + m];
        float ad = a_dst[nt * 16 + m];
#pragma unroll
        for (int r = 0; r < 4; r++) {
            int orow = row0 + quad * 4 + r;
            if (orow < N) Whb[(size_t)orow * 128 + nt * 16 + m] = f2bf(acc[r]);
            ssrc[r] += acc[r] * as;
            sdst[r] += acc[r] * ad;
        }
        if (nt & 1) {  // head h = nt>>1 complete: reduce over the 16 m-lanes
#pragma unroll
            for (int off = 1; off < 16; off <<= 1) {
#pragma unroll
                for (int r = 0; r < 4; r++) {
                    ssrc[r] += __shfl_xor(ssrc[r], off);
                    sdst[r] += __shfl_xor(sdst[r], off);
                }
            }
            if (m == 0) {
                int h = nt >> 1;
#pragma unroll
                for (int r = 0; r < 4; r++) {
                    int orow = row0 + quad * 4 + r;
                    if (orow < N) {
                        s_src[(size_t)orow * 4 + h] = ssrc[r];
                        s_dst[(size_t)orow * 4 + h] = sdst[r];
                    }
                }
            }
#pragma unroll
            for (int r = 0; r < 4; r++) { ssrc[r] = 0.f; sdst[r] = 0.f; }
        }
    }
}

// Per edge: score = ef.B + s_src[src] + s_dst[dst]; lrelu; p=exp;
// per-block partial exp-sums -> P; bucket write {src, p} at cursor[dst]++.
// 16 lanes cooperate per edge: lane j owns k = j*8..j*8+7; wave-iteration
// covers 4 consecutive edges = 2KB contiguous ef read (coalesced).
__global__ __launch_bounds__(256) void edge_kernel(
        const int* __restrict__ ei, const float* __restrict__ ef,
        const float* __restrict__ Bfold, const float* __restrict__ s_src,
        const float* __restrict__ s_dst, int* __restrict__ cursor,
        int* __restrict__ bsrc, f32x4* __restrict__ bp,
        float* __restrict__ P, int E) {
    __shared__ float psh[16];
    int tid = threadIdx.x;
    int wave = tid >> 6, lane = tid & 63;
    int g = lane >> 4, j = lane & 15;
    // per-lane B slice: B[j*8+kk][h], kept in 32 VGPRs for the whole kernel
    f32x4 Br[8];
#pragma unroll
    for (int kk = 0; kk < 8; kk++)
        Br[kk] = *(const f32x4*)(Bfold + (j * 8 + kk) * 4);
    float ps0 = 0.f, ps1 = 0.f, ps2 = 0.f, ps3 = 0.f;
    int ebase = blockIdx.x * 64 + wave * 16 + g;
#pragma unroll
    for (int it = 0; it < 4; it++) {
        int e = ebase + it * 4;
        bool valid = e < E;
        bool leader = valid && (j == 0);
        float a0 = 0.f, a1 = 0.f, a2 = 0.f, a3 = 0.f;
        int srcn = 0, dstn = 0;
        f32x4 svs = {0.f, 0.f, 0.f, 0.f}, svd = {0.f, 0.f, 0.f, 0.f};
        if (leader) {  // issue gathers early; they complete under the dot+reduce
            srcn = ei[e];
            dstn = ei[(size_t)E + e];
            svs = ((const f32x4*)s_src)[srcn];
            svd = ((const f32x4*)s_dst)[dstn];
        }
        if (valid) {
            const float* row = ef + (size_t)e * 128 + j * 8;
            f32x4 lo = *(const f32x4*)row;
            f32x4 hi = *(const f32x4*)(row + 4);
#pragma unroll
            for (int kk = 0; kk < 4; kk++) {
                float x = lo[kk], y = hi[kk];
                a0 += x * Br[kk].x + y * Br[kk + 4].x;
                a1 += x * Br[kk].y + y * Br[kk + 4].y;
                a2 += x * Br[kk].z + y * Br[kk + 4].z;
                a3 += x * Br[kk].w + y * Br[kk + 4].w;
            }
        }
        // reduce over the 16 j-lanes of this edge group
#pragma unroll
        for (int off = 1; off < 16; off <<= 1) {
            a0 += __shfl_xor(a0, off);
            a1 += __shfl_xor(a1, off);
            a2 += __shfl_xor(a2, off);
            a3 += __shfl_xor(a3, off);
        }
        if (leader) {
            float t0 = a0 + svs.x + svd.x;
            float t1 = a1 + svs.y + svd.y;
            float t2 = a2 + svs.z + svd.z;
            float t3 = a3 + svs.w + svd.w;
            t0 = t0 >= 0.f ? t0 : ALPHA * t0;
            t1 = t1 >= 0.f ? t1 : ALPHA * t1;
            t2 = t2 >= 0.f ? t2 : ALPHA * t2;
            t3 = t3 >= 0.f ? t3 : ALPHA * t3;
            float p0 = expf(t0), p1 = expf(t1), p2 = expf(t2), p3 = expf(t3);
            ps0 += p0; ps1 += p1; ps2 += p2; ps3 += p3;
            int pos = atomicAdd(&cursor[dstn], 1);
            bsrc[pos] = srcn;
            f32x4 pv = {p0, p1, p2, p3};
            bp[pos] = pv;
        }
    }
    // wave butterfly (only the 4 leader lanes hold nonzero partials)
#pragma unroll
    for (int off = 32; off > 0; off >>= 1) {
        ps0 += __shfl_xor(ps0, off);
        ps1 += __shfl_xor(ps1, off);
        ps2 += __shfl_xor(ps2, off);
        ps3 += __shfl_xor(ps3, off);
    }
    if (lane == 0) {
        psh[wave * 4 + 0] = ps0; psh[wave * 4 + 1] = ps1;
        psh[wave * 4 + 2] = ps2; psh[wave * 4 + 3] = ps3;
    }
    __syncthreads();
    if (tid < 4)
        P[(size_t)blockIdx.x * 4 + tid] = psh[tid] + psh[4 + tid] + psh[8 + tid] + psh[12 + tid];
}

// sums[h] = sum over blocks of P[b][h]; tree reduce, no atomics
__global__ void reduce_sums(const float* __restrict__ P, float* __restrict__ sums, int nb) {
    __shared__ float red[256];
    int t = threadIdx.x;
    float acc = 0.f;
    for (int b = t >> 2; b < nb; b += 64) acc += P[(size_t)b * 4 + (t & 3)];
    red[t] = acc;
    __syncthreads();
    for (int s = 128; s >= 4; s >>= 1) {
        if (t < s) red[t] += red[t + s];
        __syncthreads();
    }
    if (t < 4) sums[t] = red[t];
}

// One wave per dst node: walk bucket, acc += p[head] * Whb[src], then
// out = relu(acc) / sums[head]. Lane l owns cols 2l, 2l+1 (same head).
__global__ __launch_bounds__(256) void agg_kernel(
        const int* __restrict__ off, const int* __restrict__ bsrc,
        const float* __restrict__ bp, const unsigned short* __restrict__ Whb,
        const float* __restrict__ sums, float* __restrict__ out, int N) {
    int wave = threadIdx.x >> 6, lane = threadIdx.x & 63;
    int n = blockIdx.x * 4 + wave;
    if (n >= N) return;
    int i0 = off[n], i1 = off[n + 1];
    int head = lane >> 4;  // col = 2*lane -> head = 2*lane/32 = lane/16
    float acc0 = 0.f, acc1 = 0.f;
    for (int i = i0; i < i1; i++) {
        int src = bsrc[i];
        float ph = bp[(size_t)i * 4 + head];
        unsigned w = *(const unsigned*)(Whb + (size_t)src * 128 + lane * 2);
        acc0 += ph * bf2f((unsigned short)(w & 0xffffu));
        acc1 += ph * bf2f((unsigned short)(w >> 16));
    }
    float inv = 1.0f / sums[head];
    float2 o;
    o.x = fmaxf(acc0, 0.f) * inv;
    o.y = fmaxf(acc1, 0.f) * inv;
    *(float2*)(out + (size_t)n * 128 + lane * 2) = o;
}

extern "C" void kernel_launch(void* const* d_in, const int* in_sizes, int n_in,
                              void* d_out, int out_size, void* d_ws, size_t ws_size,
                              hipStream_t stream) {
    const int* ei = (const int*)d_in[0];
    const float* hmat = (const float*)d_in[1];
    const float* ef = (const float*)d_in[2];
    const float* W = (const float*)d_in[3];
    const float* We = (const float*)d_in[4];
    const float* a_src = (const float*)d_in[5];
    const float* a_dst = (const float*)d_in[6];
    const float* a_edge = (const float*)d_in[7];
    int E = in_sizes[0] / 2;
    int N = in_sizes[1] / 128;
    int nEdgeBlocks = (E + 63) / 64;  // 64 edges per block (16 per wave)

    char* ws = (char*)d_ws;
    size_t off_b = 0;
    auto alloc = [&](size_t bytes) -> void* {
        void* p = ws + off_b;
        off_b = (off_b + bytes + 255) & ~(size_t)255;
        return p;
    };
    unsigned short* Whb = (unsigned short*)alloc((size_t)N * 128 * 2);
    float* s_src = (float*)alloc((size_t)N * 4 * 4);
    float* s_dst = (float*)alloc((size_t)N * 4 * 4);
    float* Bfold = (float*)alloc(128 * 4 * 4);
    int* deg = (int*)alloc((size_t)N * 4);
    int* off = (int*)alloc((size_t)(N + 1) * 4);
    int* cursor = (int*)alloc((size_t)N * 4);
    int* bsrc = (int*)alloc((size_t)E * 4);
    float* bp = (float*)alloc((size_t)E * 16);
    float* P = (float*)alloc((size_t)nEdgeBlocks * 4 * 4);
    float* sums = (float*)alloc(256);

    hipMemsetAsync(deg, 0, (size_t)N * 4, stream);
    hist_fold_kernel<<<(E + 255) / 256, 256, 0, stream>>>(ei, deg, E, We, a_edge, Bfold);
    scan_kernel<<<1, 1024, 0, stream>>>(deg, off, cursor, N);
    gemm_wh<<<(N + 63) / 64, 256, 0, stream>>>(hmat, W, a_src, a_dst, Whb, s_src, s_dst, N);
    edge_kernel<<<nEdgeBlocks, 256, 0, stream>>>(ei, ef, Bfold, s_src, s_dst,
                                                 cursor, bsrc, (f32x4*)bp, P, E);
    reduce_sums<<<1, 256, 0, stream>>>(P, sums, nEdgeBlocks);
    agg_kernel<<<(N + 3) / 4, 256, 0, stream>>>(off, bsrc, bp, Whb, sums,
                                                (float*)d_out, N);
}